// Round 5
// baseline (231.338 us; speedup 1.0000x reference)
//
#include <hip/hip_runtime.h>

// Problem constants (from reference): N=1e6, D1=D2=16, NC=64 outer, NCPC=8 inner.
constexpr int D = 16;
constexpr int NC = 64;
constexpr int NCPC = 8;
constexpr int OSTRIDE = NCPC * D + 4;   // 132 floats: pad 4 so start bank = (4*o)%32, 16B aligned
constexpr int NPT = 2;                  // points per thread (fused into ONE paired pass)
constexpr int BLOCK = 512;

// R2 post-mortem: 2nd arg = min BLOCKS/CU on this toolchain (VGPR=32 at (512,8)).
// (512,2) -> VGPR cap 128: no spill risk; LDS 36.1KB allows 4 blocks/CU if VGPR<=64.
// R5: pair two points per pass so each center s_load_dwordx16 feeds 32 FMAs, not 16
// -> the ~2-load SGPR window (SGPR_Count=48) covers K$ latency; s_loads/point halved.
__global__ __launch_bounds__(BLOCK, 2)
void cluster_kernel(const float* __restrict__ x,
                    const float* __restrict__ co,
                    const float* __restrict__ ci,
                    int* __restrict__ out, int n)
{
    __shared__ __align__(16) float s_ci[NC * OSTRIDE];
    __shared__ float s_inorm[NC * 9];            // [o][k], stride 9 to spread banks

    const int t = threadIdx.x;

    // ---- Block setup: stage inner centers (8192 floats = 2048 float4) into LDS ----
    const float4* ci4 = (const float4*)ci;
    #pragma unroll
    for (int i = 0; i < (NC * NCPC * D / 4) / BLOCK; ++i) {   // 4 iters at BLOCK=512
        int idx = t + i * BLOCK;        // 0..2047
        int o = idx >> 5;               // 32 float4 per outer cluster
        int f = idx & 31;               // k*4 + d4
        float4 v = ci4[idx];
        *(float4*)&s_ci[o * OSTRIDE + f * 4] = v;
    }
    // ---- 512 inner norms, one per thread, once per block ----
    for (int i = t; i < NC * NCPC; i += BLOCK) {
        const float* src = ci + i * D;
        float s = 0.f;
        #pragma unroll
        for (int k = 0; k < D; ++k) s = fmaf(src[k], src[k], s);
        s_inorm[(i >> 3) * 9 + (i & 7)] = s;
    }
    // ---- Outer norm for center (t&63), held in a register (lane l -> ||c_l||^2) ----
    float my_norm;
    {
        const float* c = co + (t & 63) * D;
        float s = 0.f;
        #pragma unroll
        for (int k = 0; k < D; ++k) s = fmaf(c[k], c[k], s);
        my_norm = s;
    }
    __syncthreads();

    // ---- One fused pass over TWO points: p0 = base+t, p1 = p0+BLOCK ----
    const int p0 = blockIdx.x * (BLOCK * NPT) + t;
    const int p1 = p0 + BLOCK;
    const bool v0 = p0 < n, v1 = p1 < n;
    const int q0 = v0 ? p0 : 0;          // clamp: dummy-read point 0, store guarded
    const int q1 = v1 ? p1 : 0;
    const float4* xpA = (const float4*)(x + (size_t)q0 * 32);
    const float4* xpB = (const float4*)(x + (size_t)q1 * 32);

    // x1 for both points (x2 loads deferred past the outer argmin)
    float4 a0 = xpA[0], a1 = xpA[1], a2 = xpA[2], a3 = xpA[3];
    float4 b0 = xpB[0], b1 = xpB[1], b2 = xpB[2], b3 = xpB[3];
    float xA[16] = {a0.x,a0.y,a0.z,a0.w, a1.x,a1.y,a1.z,a1.w,
                    a2.x,a2.y,a2.z,a2.w, a3.x,a3.y,a3.z,a3.w};
    float xB[16] = {b0.x,b0.y,b0.z,b0.w, b1.x,b1.y,b1.z,b1.w,
                    b2.x,b2.y,b2.z,b2.w, b3.x,b3.y,b3.z,b3.w};

    // ---- Outer argmin, both points per center s_load. Per-point fma chain is
    //      bit-identical to the passing kernel (no reassociation). ----
    float bestdA = 3.4e38f, bestdB = 3.4e38f;
    int boA = 0, boB = 0;
    #pragma unroll
    for (int j = 0; j < NC; ++j) {
        const float* c = co + j * D;
        float dA = 0.f, dB = 0.f;
        #pragma unroll
        for (int k = 0; k < D; ++k) {
            float ck = c[k];
            dA = fmaf(xA[k], ck, dA);
            dB = fmaf(xB[k], ck, dB);
        }
        float nj = __int_as_float(
            __builtin_amdgcn_readlane(__float_as_int(my_norm), j));
        float ddA = fmaf(-2.f, dA, nj);
        float ddB = fmaf(-2.f, dB, nj);
        if (ddA < bestdA) { bestdA = ddA; boA = j; }   // strict <: first index wins
        if (ddB < bestdB) { bestdB = ddB; boB = j; }
    }

    // ---- x2 for both points (x1 registers dead -> reusable) ----
    float4 c0_ = xpA[4], c1_ = xpA[5], c2_ = xpA[6], c3_ = xpA[7];
    float4 d0_ = xpB[4], d1_ = xpB[5], d2_ = xpB[6], d3_ = xpB[7];
    float yA[16] = {c0_.x,c0_.y,c0_.z,c0_.w, c1_.x,c1_.y,c1_.z,c1_.w,
                    c2_.x,c2_.y,c2_.z,c2_.w, c3_.x,c3_.y,c3_.z,c3_.w};
    float yB[16] = {d0_.x,d0_.y,d0_.z,d0_.w, d1_.x,d1_.y,d1_.z,d1_.w,
                    d2_.x,d2_.y,d2_.z,d2_.w, d3_.x,d3_.y,d3_.z,d3_.w};

    // ---- Inner argmin for point A (LDS gather over bo's 8 sub-centers) ----
    int bkA = 0;
    {
        const float* cb = s_ci + boA * OSTRIDE;
        const float* nb = s_inorm + boA * 9;
        float bestd2 = 3.4e38f;
        #pragma unroll
        for (int k = 0; k < NCPC; ++k) {
            float4 e0 = *(const float4*)&cb[k * D + 0];
            float4 e1 = *(const float4*)&cb[k * D + 4];
            float4 e2 = *(const float4*)&cb[k * D + 8];
            float4 e3 = *(const float4*)&cb[k * D + 12];
            float dot = 0.f;
            dot = fmaf(yA[0],  e0.x, dot); dot = fmaf(yA[1],  e0.y, dot);
            dot = fmaf(yA[2],  e0.z, dot); dot = fmaf(yA[3],  e0.w, dot);
            dot = fmaf(yA[4],  e1.x, dot); dot = fmaf(yA[5],  e1.y, dot);
            dot = fmaf(yA[6],  e1.z, dot); dot = fmaf(yA[7],  e1.w, dot);
            dot = fmaf(yA[8],  e2.x, dot); dot = fmaf(yA[9],  e2.y, dot);
            dot = fmaf(yA[10], e2.z, dot); dot = fmaf(yA[11], e2.w, dot);
            dot = fmaf(yA[12], e3.x, dot); dot = fmaf(yA[13], e3.y, dot);
            dot = fmaf(yA[14], e3.z, dot); dot = fmaf(yA[15], e3.w, dot);
            float d2v = fmaf(-2.f, dot, nb[k]);
            if (d2v < bestd2) { bestd2 = d2v; bkA = k; }
        }
    }
    // ---- Inner argmin for point B ----
    int bkB = 0;
    {
        const float* cb = s_ci + boB * OSTRIDE;
        const float* nb = s_inorm + boB * 9;
        float bestd2 = 3.4e38f;
        #pragma unroll
        for (int k = 0; k < NCPC; ++k) {
            float4 e0 = *(const float4*)&cb[k * D + 0];
            float4 e1 = *(const float4*)&cb[k * D + 4];
            float4 e2 = *(const float4*)&cb[k * D + 8];
            float4 e3 = *(const float4*)&cb[k * D + 12];
            float dot = 0.f;
            dot = fmaf(yB[0],  e0.x, dot); dot = fmaf(yB[1],  e0.y, dot);
            dot = fmaf(yB[2],  e0.z, dot); dot = fmaf(yB[3],  e0.w, dot);
            dot = fmaf(yB[4],  e1.x, dot); dot = fmaf(yB[5],  e1.y, dot);
            dot = fmaf(yB[6],  e1.z, dot); dot = fmaf(yB[7],  e1.w, dot);
            dot = fmaf(yB[8],  e2.x, dot); dot = fmaf(yB[9],  e2.y, dot);
            dot = fmaf(yB[10], e2.z, dot); dot = fmaf(yB[11], e2.w, dot);
            dot = fmaf(yB[12], e3.x, dot); dot = fmaf(yB[13], e3.y, dot);
            dot = fmaf(yB[14], e3.z, dot); dot = fmaf(yB[15], e3.w, dot);
            float d2v = fmaf(-2.f, dot, nb[k]);
            if (d2v < bestd2) { bestd2 = d2v; bkB = k; }
        }
    }

    if (v0) out[p0] = boA * NCPC + bkA;
    if (v1) out[p1] = boB * NCPC + bkB;
}

extern "C" void kernel_launch(void* const* d_in, const int* in_sizes, int n_in,
                              void* d_out, int out_size, void* d_ws, size_t ws_size,
                              hipStream_t stream) {
    const float* x  = (const float*)d_in[0];   // (N, 32) fp32
    const float* co = (const float*)d_in[1];   // (64, 16) fp32
    const float* ci = (const float*)d_in[2];   // (64, 8, 16) fp32
    int* out = (int*)d_out;                    // (N,) int32
    int n = in_sizes[0] / 32;
    int blocks = (n + BLOCK * NPT - 1) / (BLOCK * NPT);
    cluster_kernel<<<blocks, BLOCK, 0, stream>>>(x, co, ci, out, n);
}

// Round 6
// 191.889 us; speedup vs baseline: 1.2056x; 1.2056x over previous
//
#include <hip/hip_runtime.h>

// N=1e6, D1=D2=16, NC=64 outer, NCPC=8 inner.
// R6: outer stage via v_mfma_f32_32x32x16_bf16 with swapped operands
// (A=centers, B=points) and 3-way bf16 splits; centers live in 24 VGPRs as
// fragments, norms folded into the accumulator init. This removes the
// per-point serial 64x s_load center walk (the measured ~94% per-wave stall).
constexpr int D = 16;
constexpr int NC = 64;
constexpr int NCPC = 8;
constexpr int OSTRIDE = NCPC * D + 4;   // 132 floats
constexpr int BLOCK = 256;              // 4 waves/block
constexpr int NPT = 4;                  // passes; 64 pts/wave/pass -> 1024 pts/block

typedef __attribute__((ext_vector_type(8)))  short short8;   // 8 bf16 = 4 VGPRs
typedef __attribute__((ext_vector_type(16))) float f32x16;   // MFMA 32x32 acc

static __device__ __forceinline__ unsigned f2bf(float f) {   // RNE fp32->bf16 bits
    unsigned u = __float_as_uint(f);
    u += 0x7FFFu + ((u >> 16) & 1u);
    return u >> 16;
}
static __device__ __forceinline__ float bf2f(unsigned h) {
    return __uint_as_float(h << 16);
}

__global__ __launch_bounds__(BLOCK, 4)   // 4 blocks/CU (LDS 36.1KB) -> VGPR cap 128
void cluster_kernel(const float* __restrict__ x,
                    const float* __restrict__ co,
                    const float* __restrict__ ci,
                    int* __restrict__ out, int n)
{
    __shared__ __align__(16) float s_ci[NC * OSTRIDE];   // 33792 B
    __shared__ float s_inorm[NC * 9];                    // 2304 B

    const int t    = threadIdx.x;
    const int lane = t & 63;
    const int wave = t >> 6;

    // ---- Stage inner centers (2048 float4) ----
    const float4* ci4 = (const float4*)ci;
    #pragma unroll
    for (int i = 0; i < 8; ++i) {
        int idx = t + i * BLOCK;
        int o = idx >> 5, f = idx & 31;
        float4 v = ci4[idx];
        *(float4*)&s_ci[o * OSTRIDE + f * 4] = v;
    }
    // ---- 512 inner norms ----
    #pragma unroll
    for (int ii = 0; ii < 2; ++ii) {
        int i = t + ii * BLOCK;
        const float* src = ci + i * D;
        float s = 0.f;
        #pragma unroll
        for (int k = 0; k < D; ++k) s = fmaf(src[k], src[k], s);
        s_inorm[(i >> 3) * 9 + (i & 7)] = s;
    }

    // ---- Outer norms: lane holds ||co[lane]||^2 ----
    float my_norm;
    {
        const float* c = co + lane * D;
        float s = 0.f;
        #pragma unroll
        for (int k = 0; k < D; ++k) s = fmaf(c[k], c[k], s);
        my_norm = s;
    }

    const int hi  = lane >> 5;   // which k-slice / acc row-half
    const int ks  = hi * 8;      // k-slice start (A/B frag: k = ks + j)
    const int hi4 = hi * 4;      // acc row offset term 4*(lane>>5)

    // ---- Acc-init norms: n_init[tc][r] = ||co[c(tc,r,lane)]||^2 via bpermute ----
    // C/D layout (m74/m101): col=lane&31, row=(r&3)+8*(r>>2)+4*(lane>>5)
    float n_init[2][16];
    #pragma unroll
    for (int tc = 0; tc < 2; ++tc) {
        #pragma unroll
        for (int r = 0; r < 16; ++r) {
            int c = tc * 32 + (r & 3) + 8 * (r >> 2) + hi4;
            n_init[tc][r] = __int_as_float(
                __builtin_amdgcn_ds_bpermute(c << 2, __float_as_int(my_norm)));
        }
    }

    // ---- A-frags (centers), resident for whole kernel: 2 ctr-tiles x {h,m,l} ----
    // A layout: row = lane&31, k = (lane>>5)*8 + j
    short8 a_h[2], a_m[2], a_l[2];
    #pragma unroll
    for (int tc = 0; tc < 2; ++tc) {
        const float* cp = co + (tc * 32 + (lane & 31)) * D + ks;
        float4 v0 = *(const float4*)cp;
        float4 v1 = *(const float4*)(cp + 4);
        float vv[8] = {v0.x,v0.y,v0.z,v0.w, v1.x,v1.y,v1.z,v1.w};
        #pragma unroll
        for (int j = 0; j < 8; ++j) {
            float v = vv[j];
            unsigned h = f2bf(v); float r1 = v - bf2f(h);
            unsigned m = f2bf(r1); r1 = r1 - bf2f(m);
            unsigned l2 = f2bf(r1);
            a_h[tc][j] = (short)h; a_m[tc][j] = (short)m; a_l[tc][j] = (short)l2;
        }
    }
    __syncthreads();

    const int blockStart = blockIdx.x * (BLOCK * NPT);
    #pragma unroll 1                     // keep body small for I-cache
    for (int it = 0; it < NPT; ++it) {
        const int S = blockStart + it * BLOCK + wave * 64;   // wave's 64 points

        int bo0 = 0, bo1 = 0;
        #pragma unroll
        for (int pt = 0; pt < 2; ++pt) {
            // ---- B-frags: point P = S + pt*32 + (lane&31), k = ks + j, scaled by -2 ----
            int P = S + pt * 32 + (lane & 31);
            P = P < n ? P : n - 1;                 // clamp (col-independent results)
            const float* xp = x + (size_t)P * 32 + ks;
            float4 w0 = *(const float4*)xp;
            float4 w1 = *(const float4*)(xp + 4);
            float vv[8] = {w0.x,w0.y,w0.z,w0.w, w1.x,w1.y,w1.z,w1.w};
            short8 b_h, b_m, b_l;
            #pragma unroll
            for (int j = 0; j < 8; ++j) {
                float v = -2.0f * vv[j];           // exact
                unsigned h = f2bf(v); float r1 = v - bf2f(h);
                unsigned m = f2bf(r1); r1 = r1 - bf2f(m);
                unsigned l2 = f2bf(r1);
                b_h[j] = (short)h; b_m[j] = (short)m; b_l[j] = (short)l2;
            }

            // ---- acc = norms + centers·(-2x): 6 split-terms per ctr-tile ----
            f32x16 acc0, acc1;
            #pragma unroll
            for (int r = 0; r < 16; ++r) { acc0[r] = n_init[0][r]; acc1[r] = n_init[1][r]; }
            acc0 = __builtin_amdgcn_mfma_f32_32x32x16_bf16(a_h[0], b_h, acc0, 0,0,0);
            acc0 = __builtin_amdgcn_mfma_f32_32x32x16_bf16(a_h[0], b_m, acc0, 0,0,0);
            acc0 = __builtin_amdgcn_mfma_f32_32x32x16_bf16(a_m[0], b_h, acc0, 0,0,0);
            acc0 = __builtin_amdgcn_mfma_f32_32x32x16_bf16(a_h[0], b_l, acc0, 0,0,0);
            acc0 = __builtin_amdgcn_mfma_f32_32x32x16_bf16(a_m[0], b_m, acc0, 0,0,0);
            acc0 = __builtin_amdgcn_mfma_f32_32x32x16_bf16(a_l[0], b_h, acc0, 0,0,0);
            acc1 = __builtin_amdgcn_mfma_f32_32x32x16_bf16(a_h[1], b_h, acc1, 0,0,0);
            acc1 = __builtin_amdgcn_mfma_f32_32x32x16_bf16(a_h[1], b_m, acc1, 0,0,0);
            acc1 = __builtin_amdgcn_mfma_f32_32x32x16_bf16(a_m[1], b_h, acc1, 0,0,0);
            acc1 = __builtin_amdgcn_mfma_f32_32x32x16_bf16(a_h[1], b_l, acc1, 0,0,0);
            acc1 = __builtin_amdgcn_mfma_f32_32x32x16_bf16(a_m[1], b_m, acc1, 0,0,0);
            acc1 = __builtin_amdgcn_mfma_f32_32x32x16_bf16(a_l[1], b_h, acc1, 0,0,0);

            // ---- Within-lane argmin over 32 centers (scan in increasing index;
            //      strict < keeps first index on ties, matching np.argmin) ----
            float bestd = 3.4e38f; int bc = 0;
            #pragma unroll
            for (int tc = 0; tc < 2; ++tc) {
                #pragma unroll
                for (int r = 0; r < 16; ++r) {
                    float d  = tc ? acc1[r] : acc0[r];
                    int  cb = tc * 32 + (r & 3) + 8 * (r >> 2);  // + hi4 later
                    if (d < bestd) { bestd = d; bc = cb; }
                }
            }
            int bestc = bc + hi4;
            // ---- Cross-half merge (lane <-> lane^32), index tie-break ----
            int pidx = (lane ^ 32) << 2;
            float od = __int_as_float(
                __builtin_amdgcn_ds_bpermute(pidx, __float_as_int(bestd)));
            int   oc = __builtin_amdgcn_ds_bpermute(pidx, bestc);
            if (od < bestd || (od == bestd && oc < bestc)) { bestd = od; bestc = oc; }
            if (pt == 0) bo0 = bestc; else bo1 = bestc;
        }
        // lane owns point S+lane: tile0 col=lane (lane<32), tile1 col=lane-32
        const int bo = (lane < 32) ? bo0 : bo1;

        // ---- Inner argmin (unchanged): own point's x2 vs bo's 8 sub-centers ----
        const int p = S + lane;
        const int q = p < n ? p : n - 1;
        const float4* yp = (const float4*)(x + (size_t)q * 32 + 16);
        float4 ya = yp[0], yb = yp[1], yc = yp[2], yd = yp[3];
        float x2[16] = {ya.x,ya.y,ya.z,ya.w, yb.x,yb.y,yb.z,yb.w,
                        yc.x,yc.y,yc.z,yc.w, yd.x,yd.y,yd.z,yd.w};
        const float* cbp = s_ci + bo * OSTRIDE;
        const float* nb  = s_inorm + bo * 9;
        float bestd2 = 3.4e38f;
        int bk = 0;
        #pragma unroll
        for (int k = 0; k < NCPC; ++k) {
            float4 e0 = *(const float4*)&cbp[k * D + 0];
            float4 e1 = *(const float4*)&cbp[k * D + 4];
            float4 e2 = *(const float4*)&cbp[k * D + 8];
            float4 e3 = *(const float4*)&cbp[k * D + 12];
            float dot = 0.f;
            dot = fmaf(x2[0],  e0.x, dot); dot = fmaf(x2[1],  e0.y, dot);
            dot = fmaf(x2[2],  e0.z, dot); dot = fmaf(x2[3],  e0.w, dot);
            dot = fmaf(x2[4],  e1.x, dot); dot = fmaf(x2[5],  e1.y, dot);
            dot = fmaf(x2[6],  e1.z, dot); dot = fmaf(x2[7],  e1.w, dot);
            dot = fmaf(x2[8],  e2.x, dot); dot = fmaf(x2[9],  e2.y, dot);
            dot = fmaf(x2[10], e2.z, dot); dot = fmaf(x2[11], e2.w, dot);
            dot = fmaf(x2[12], e3.x, dot); dot = fmaf(x2[13], e3.y, dot);
            dot = fmaf(x2[14], e3.z, dot); dot = fmaf(x2[15], e3.w, dot);
            float d2v = fmaf(-2.f, dot, nb[k]);
            if (d2v < bestd2) { bestd2 = d2v; bk = k; }
        }

        if (p < n) out[p] = bo * NCPC + bk;
    }
}

extern "C" void kernel_launch(void* const* d_in, const int* in_sizes, int n_in,
                              void* d_out, int out_size, void* d_ws, size_t ws_size,
                              hipStream_t stream) {
    const float* x  = (const float*)d_in[0];   // (N, 32) fp32
    const float* co = (const float*)d_in[1];   // (64, 16) fp32
    const float* ci = (const float*)d_in[2];   // (64, 8, 16) fp32
    int* out = (int*)d_out;                    // (N,) int32
    int n = in_sizes[0] / 32;
    int blocks = (n + BLOCK * NPT - 1) / (BLOCK * NPT);
    cluster_kernel<<<blocks, BLOCK, 0, stream>>>(x, co, ci, out, n);
}